// Round 8
// baseline (417.924 us; speedup 1.0000x reference)
//
#include <hip/hip_runtime.h>

#define NNODES 16384
#define EDGES  262144
#define DH     128
#define NH     8
#define CH     16
#define NL     6
#define SEQ    128
#define NNPG   64

typedef short bf16x8 __attribute__((ext_vector_type(8)));
typedef float f32x4 __attribute__((ext_vector_type(4)));
typedef float f32x2 __attribute__((ext_vector_type(2)));

static __device__ __forceinline__ unsigned short f2bf(float f) {
  unsigned u = __float_as_uint(f);
  u += 0x7FFFu + ((u >> 16) & 1u);   // round-to-nearest-even
  return (unsigned short)(u >> 16);
}
static __device__ __forceinline__ float bfl(unsigned u) { return __uint_as_float(u << 16); }
static __device__ __forceinline__ float bfh(unsigned u) { return __uint_as_float(u & 0xffff0000u); }

// ---------------- h0 = x@Win + bin + pe (fp32 h + bf16 h) ----------------
__global__ __launch_bounds__(128) void k_input(const float* __restrict__ x,
    const float* __restrict__ Win, const float* __restrict__ bin,
    const float* __restrict__ pe, float* __restrict__ h,
    unsigned short* __restrict__ hb) {
  const int n = blockIdx.x, d = threadIdx.x;
  __shared__ float xs[9];
  if (d < 9) xs[d] = x[n * 9 + d];
  __syncthreads();
  float acc = bin[d];
#pragma unroll
  for (int f = 0; f < 9; ++f) acc = fmaf(xs[f], Win[f * DH + d], acc);
  const float val = acc + pe[((n / NNPG) % SEQ) * DH + d];
  h[n * DH + d] = val;
  hb[n * DH + d] = f2bf(val);
}

// ---------------- CSR build (dst-grouped), once per call ----------------
__global__ __launch_bounds__(256) void k_count(const int* __restrict__ ei,
                                               int* __restrict__ cnt) {
  const int e = blockIdx.x * 256 + threadIdx.x;
  atomicAdd(&cnt[ei[EDGES + e]], 1);
}

__global__ __launch_bounds__(1024) void k_scan(int* __restrict__ cnt,
                                               int* __restrict__ row_start) {
  __shared__ int part[1024];
  const int t = threadIdx.x;
  int loc[16];
  int s = 0;
  const int base = t * 16;
#pragma unroll
  for (int i = 0; i < 16; ++i) { loc[i] = cnt[base + i]; s += loc[i]; }
  part[t] = s;
  __syncthreads();
  for (int off = 1; off < 1024; off <<= 1) {
    int add = (t >= off) ? part[t - off] : 0;
    __syncthreads();
    part[t] += add;
    __syncthreads();
  }
  int run = (t == 0) ? 0 : part[t - 1];
#pragma unroll
  for (int i = 0; i < 16; ++i) {
    row_start[base + i] = run;
    run += loc[i];
    cnt[base + i] = 0;  // reused as cursor by k_fill
  }
  if (t == 0) row_start[NNODES] = EDGES;
}

__global__ __launch_bounds__(256) void k_fill(const int* __restrict__ ei,
    const int* __restrict__ row_start, int* __restrict__ cursor,
    int* __restrict__ csr_src, int* __restrict__ csr_dst) {
  const int e = blockIdx.x * 256 + threadIdx.x;
  const int d = ei[EDGES + e];
  const int pos = row_start[d] + atomicAdd(&cursor[d], 1);
  csr_src[pos] = ei[e];
  csr_dst[pos] = d;
}

// ---------------- weight convert+swizzle to MFMA B-fragment order ----------------
__global__ __launch_bounds__(64) void k_wconv(const float* __restrict__ Wq,
    const float* __restrict__ Wk, const float* __restrict__ Wv,
    const float* __restrict__ Ws, unsigned short* __restrict__ Wf) {
  const int bid = blockIdx.x;
  const int layer = bid >> 7, rem = bid & 127;
  const int mat = rem >> 5, tile = rem & 31;
  const int nt = tile >> 2, kt = tile & 3;
  const int lane = threadIdx.x;
  const float* W = ((mat == 0) ? Wq : (mat == 1) ? Wk : (mat == 2) ? Wv : Ws)
                   + layer * DH * DH;
  const int n = nt * 16 + (lane & 15);
  const int k0 = kt * 32 + (lane >> 4) * 8;
  unsigned pk[4];
#pragma unroll
  for (int jj = 0; jj < 4; ++jj) {
    const unsigned lo = f2bf(W[(k0 + 2 * jj) * DH + n]);
    const unsigned hi = f2bf(W[(k0 + 2 * jj + 1) * DH + n]);
    pk[jj] = lo | (hi << 16);
  }
  uint4 o = {pk[0], pk[1], pk[2], pk[3]};
  *(uint4*)&Wf[(((layer * 4 + mat) * 32 + tile) * 64 + lane) * 8] = o;
}

// ---------------- fused Q/K/V/skip GEMM via bf16 MFMA ----------------
// grid (512, 2) x 256 thr; wave = one 32x64 output tile. q->bf16, k/v->fp8, s->fp32.
__global__ __launch_bounds__(256) void k_gemm(const unsigned short* __restrict__ hb,
    const unsigned short* __restrict__ Wf,
    const float* __restrict__ bq, const float* __restrict__ bk,
    const float* __restrict__ bv, const float* __restrict__ bs,
    unsigned short* __restrict__ qb, unsigned char* __restrict__ kb8,
    unsigned char* __restrict__ vb8, float* __restrict__ xr) {
  const int mt = blockIdx.x;
  const int wv = threadIdx.x >> 6, lane = threadIdx.x & 63;
  const int g = blockIdx.y * 4 + wv;           // col group 0..7 (64 cols)
  const int mat = g >> 1, nbase = (g & 1) * 64;
  const unsigned short* Wm = Wf + mat * 16384;
  const float* bias = (mat == 0) ? bq : (mat == 1) ? bk : (mat == 2) ? bv : bs;
  const int m0 = lane & 15, quad = lane >> 4;
  const int nt0 = (g & 1) * 4;

  const f32x4 z = {0.f, 0.f, 0.f, 0.f};
  f32x4 acc[2][4] = {{z, z, z, z}, {z, z, z, z}};
#pragma unroll
  for (int kt = 0; kt < 4; ++kt) {
    const bf16x8 a0 = *(const bf16x8*)&hb[(mt * 32 + m0) * DH + kt * 32 + quad * 8];
    const bf16x8 a1 = *(const bf16x8*)&hb[(mt * 32 + 16 + m0) * DH + kt * 32 + quad * 8];
#pragma unroll
    for (int j = 0; j < 4; ++j) {
      const bf16x8 b = *(const bf16x8*)&Wm[(((nt0 + j) * 4 + kt) * 64 + lane) * 8];
      acc[0][j] = __builtin_amdgcn_mfma_f32_16x16x32_bf16(a0, b, acc[0][j], 0, 0, 0);
      acc[1][j] = __builtin_amdgcn_mfma_f32_16x16x32_bf16(a1, b, acc[1][j], 0, 0, 0);
    }
  }
  unsigned char* __restrict__ f8dst = (mat == 1) ? kb8 : vb8;
#pragma unroll
  for (int half = 0; half < 2; ++half) {
#pragma unroll
    for (int j = 0; j < 4; ++j) {
      const int col = nbase + j * 16 + m0;
      const float bvv = bias[col];
#pragma unroll
      for (int r = 0; r < 4; ++r) {
        const float val = acc[half][j][r] + bvv;
        const int row = mt * 32 + half * 16 + quad * 4 + r;
        if (mat == 0) {
          qb[row * DH + col] = f2bf(val);
        } else if (mat == 3) {
          xr[row * DH + col] = val;
        } else {
          // pair lanes (even,odd cols) -> 2 fp8 packed, even lane stores ushort
          const float nbv = __shfl_xor(val, 1);
          if ((lane & 1) == 0) {
            const int pk = __builtin_amdgcn_cvt_pk_fp8_f32(val, nbv, 0, false);
            *(unsigned short*)&f8dst[row * DH + col] = (unsigned short)pk;
          }
        }
      }
    }
  }
}

// ---------------- shared helpers ----------------
__device__ __forceinline__ void load16bf(const unsigned short* __restrict__ p, float* r) {
  const uint4 a = *(const uint4*)p;
  const uint4 b = *(const uint4*)(p + 8);
  r[0] = bfl(a.x); r[1] = bfh(a.x); r[2] = bfl(a.y); r[3] = bfh(a.y);
  r[4] = bfl(a.z); r[5] = bfh(a.z); r[6] = bfl(a.w); r[7] = bfh(a.w);
  r[8] = bfl(b.x); r[9] = bfh(b.x); r[10] = bfl(b.y); r[11] = bfh(b.y);
  r[12] = bfl(b.z); r[13] = bfh(b.z); r[14] = bfl(b.w); r[15] = bfh(b.w);
}

__device__ __forceinline__ void decode16f8(const uint4 u, float* r) {
  f32x2 t;
  t = __builtin_amdgcn_cvt_pk_f32_fp8(u.x, false); r[0] = t[0]; r[1] = t[1];
  t = __builtin_amdgcn_cvt_pk_f32_fp8(u.x, true);  r[2] = t[0]; r[3] = t[1];
  t = __builtin_amdgcn_cvt_pk_f32_fp8(u.y, false); r[4] = t[0]; r[5] = t[1];
  t = __builtin_amdgcn_cvt_pk_f32_fp8(u.y, true);  r[6] = t[0]; r[7] = t[1];
  t = __builtin_amdgcn_cvt_pk_f32_fp8(u.z, false); r[8] = t[0]; r[9] = t[1];
  t = __builtin_amdgcn_cvt_pk_f32_fp8(u.z, true);  r[10] = t[0]; r[11] = t[1];
  t = __builtin_amdgcn_cvt_pk_f32_fp8(u.w, false); r[12] = t[0]; r[13] = t[1];
  t = __builtin_amdgcn_cvt_pk_f32_fp8(u.w, true);  r[14] = t[0]; r[15] = t[1];
}

// ---------------- pass 1: edge-parallel scores ----------------
// one lane per (edge, head): wave = 8 edges x 8 heads. CSR-ordered edges =>
// q[dst] rows repeat across consecutive edges (L1 hits); only K (2 MB) is gathered.
__global__ __launch_bounds__(256) void k_score(const unsigned short* __restrict__ qb,
    const unsigned char* __restrict__ kb8, const int* __restrict__ csr_src,
    const int* __restrict__ csr_dst, float* __restrict__ ex) {
  const int wv = threadIdx.x >> 6, lane = threadIdx.x & 63;
  const int el = lane >> 3, hd = lane & 7;
  const int j = blockIdx.x * 32 + wv * 8 + el;
  const int s = csr_src[j];
  const int d = csr_dst[j];
  float qr[16], kr[16];
  load16bf(&qb[d * DH + hd * CH], qr);
  const uint4 ku = *(const uint4*)&kb8[s * DH + hd * CH];
  decode16f8(ku, kr);
  float dot = 0.f;
#pragma unroll
  for (int c = 0; c < 16; ++c) dot = fmaf(qr[c], kr[c], dot);
  ex[j * 8 + hd] = __expf(dot * 0.25f);  // softmax shift-invariant; scores tiny
}

// ---------------- pass 2: aggregate + beta gate + residual + LayerNorm ----------------
// One wave per node, lane = es*8 + hd. Lane (es,hd) owns agg elements
// d = hd*16 + es*2 and d+1 after the cross-slot reduction.
__device__ __forceinline__ void v_acc(const uint4 vu, float w,
    float* __restrict__ acc, float& denom) {
  float vr[16];
  decode16f8(vu, vr);
  denom += w;
#pragma unroll
  for (int c = 0; c < 16; ++c) acc[c] = fmaf(w, vr[c], acc[c]);
}

__global__ __launch_bounds__(256) void k_attn_epi(
    const unsigned char* __restrict__ vb8, const float* __restrict__ ex,
    const int* __restrict__ row_start, const int* __restrict__ csr_src,
    float* __restrict__ h, unsigned short* __restrict__ hb,
    const float* __restrict__ xr,
    const float* __restrict__ Wb, const float* __restrict__ bb,
    const float* __restrict__ ln_g, const float* __restrict__ ln_b) {
  const int wv = threadIdx.x >> 6, lane = threadIdx.x & 63;
  const int n = blockIdx.x * 4 + wv;
  const int es = lane >> 3, hd = lane & 7;   // 8 edge-slots x 8 heads
  const int beg = row_start[n], end = row_start[n + 1];
  // --- batched prefetch: up to 4 edges per lane, all loads in flight ---
  const int j0 = beg + es;
  int idx[4];
#pragma unroll
  for (int t = 0; t < 4; ++t) {
    const int jt = j0 + 8 * t;
    idx[t] = (jt < end) ? csr_src[jt] : -1;
  }
  float w[4];
  uint4 vf[4];
#pragma unroll
  for (int t = 0; t < 4; ++t) {
    const int jt = j0 + 8 * t;
    w[t] = (idx[t] >= 0) ? ex[jt * 8 + hd] : 0.f;
    const int s = (idx[t] >= 0) ? idx[t] : 0;
    vf[t] = *(const uint4*)&vb8[s * DH + hd * CH];
  }
  float acc[16] = {};
  float denom = 0.f;
#pragma unroll
  for (int t = 0; t < 4; ++t) v_acc(vf[t], w[t], acc, denom);
  // rare tail (degree > 32)
  for (int j = j0 + 32; j < end; j += 8) {
    const int s = csr_src[j];
    const uint4 vu = *(const uint4*)&vb8[s * DH + hd * CH];
    v_acc(vu, ex[j * 8 + hd], acc, denom);
  }
  // reduce across the 8 edge-slots (lane bits 3..5)
#pragma unroll
  for (int off = 8; off <= 32; off <<= 1) {
    denom += __shfl_xor(denom, off);
#pragma unroll
    for (int c = 0; c < 16; ++c) acc[c] += __shfl_xor(acc[c], off);
  }
  const float inv = 1.f / (denom + 1e-16f);
  float o0 = 0.f, o1 = 0.f;
#pragma unroll
  for (int c = 0; c < 8; ++c) {  // static select (avoid dynamic reg indexing)
    if (es == c) { o0 = acc[2 * c]; o1 = acc[2 * c + 1]; }
  }
  // --- epilogue: this lane owns agg elements d0, d0+1 ---
  const int d0 = hd * CH + es * 2;
  const float ax = o0 * inv, ay = o1 * inv;
  const float2 r = *(const float2*)&xr[n * DH + d0];
  const float2 w0 = *(const float2*)&Wb[d0];
  const float2 w1 = *(const float2*)&Wb[DH + d0];
  const float2 w2 = *(const float2*)&Wb[2 * DH + d0];
  float p = ax * w0.x + ay * w0.y + r.x * w1.x + r.y * w1.y
          + (ax - r.x) * w2.x + (ay - r.y) * w2.y;
#pragma unroll
  for (int off = 1; off <= 32; off <<= 1) p += __shfl_xor(p, off);
  const float beta = 1.f / (1.f + __expf(-(p + bb[0])));
  const float2 hv = *(const float2*)&h[n * DH + d0];
  const float t0 = hv.x + beta * r.x + (1.f - beta) * ax;
  const float t1 = hv.y + beta * r.y + (1.f - beta) * ay;
  float sum = t0 + t1, sq = t0 * t0 + t1 * t1;
#pragma unroll
  for (int off = 1; off <= 32; off <<= 1) {
    sum += __shfl_xor(sum, off);
    sq  += __shfl_xor(sq, off);
  }
  const float mu = sum * (1.f / DH);
  const float rinv = rsqrtf(sq * (1.f / DH) - mu * mu + 1e-5f);
  const float2 g = *(const float2*)&ln_g[d0];
  const float2 b = *(const float2*)&ln_b[d0];
  float2 o = {(t0 - mu) * rinv * g.x + b.x, (t1 - mu) * rinv * g.y + b.y};
  *(float2*)&h[n * DH + d0] = o;
  const unsigned lo = f2bf(o.x), hi = f2bf(o.y);
  *(unsigned*)&hb[n * DH + d0] = lo | (hi << 16);
}

// ---------------- output MLP: relu(h@Wo1+bo1)@Wo2+bo2, one wave per node ----------------
__global__ __launch_bounds__(256) void k_final(const float* __restrict__ h,
    const float* __restrict__ Wo1, const float* __restrict__ bo1,
    const float* __restrict__ Wo2, const float* __restrict__ bo2,
    float* __restrict__ out) {
  __shared__ float hs[4][DH];
  const int lane = threadIdx.x & 63, wid = threadIdx.x >> 6;
  const int n = blockIdx.x * 4 + wid;
  const float2 hv = *(const float2*)&h[n * DH + lane * 2];
  hs[wid][lane * 2] = hv.x;
  hs[wid][lane * 2 + 1] = hv.y;
  __syncthreads();
  float m = bo1[lane];
#pragma unroll 16
  for (int d = 0; d < DH; ++d) m = fmaf(hs[wid][d], Wo1[d * 64 + lane], m);
  m = fmaxf(m, 0.f);
  float o0 = m * Wo2[lane * 3 + 0];
  float o1 = m * Wo2[lane * 3 + 1];
  float o2 = m * Wo2[lane * 3 + 2];
#pragma unroll
  for (int off = 32; off; off >>= 1) {
    o0 += __shfl_xor(o0, off);
    o1 += __shfl_xor(o1, off);
    o2 += __shfl_xor(o2, off);
  }
  if (lane == 0) {
    out[n * 3 + 0] = o0 + bo2[0];
    out[n * 3 + 1] = o1 + bo2[1];
    out[n * 3 + 2] = o2 + bo2[2];
  }
}

extern "C" void kernel_launch(void* const* d_in, const int* in_sizes, int n_in,
                              void* d_out, int out_size, void* d_ws, size_t ws_size,
                              hipStream_t stream) {
  const float* x   = (const float*)d_in[0];
  const int*   ei  = (const int*)d_in[1];
  const float* pe  = (const float*)d_in[2];
  const float* Win = (const float*)d_in[3];
  const float* bin = (const float*)d_in[4];
  const float* Wq  = (const float*)d_in[5];
  const float* bq  = (const float*)d_in[6];
  const float* Wk  = (const float*)d_in[7];
  const float* bk  = (const float*)d_in[8];
  const float* Wv  = (const float*)d_in[9];
  const float* bv  = (const float*)d_in[10];
  const float* Wsk = (const float*)d_in[11];
  const float* bs  = (const float*)d_in[12];
  const float* Wb  = (const float*)d_in[13];
  const float* bb  = (const float*)d_in[14];
  const float* lng = (const float*)d_in[15];
  const float* lnb = (const float*)d_in[16];
  const float* Wo1 = (const float*)d_in[17];
  const float* bo1 = (const float*)d_in[18];
  const float* Wo2 = (const float*)d_in[19];
  const float* bo2 = (const float*)d_in[20];

  const size_t NU = (size_t)NNODES * DH;
  char* base = (char*)d_ws;
  float* h   = (float*)base;                  base += NU * 4;
  float* xr  = (float*)base;                  base += NU * 4;
  unsigned short* hb = (unsigned short*)base; base += NU * 2;
  unsigned short* qb = (unsigned short*)base; base += NU * 2;
  unsigned char* kb8 = (unsigned char*)base;  base += NU;
  unsigned char* vb8 = (unsigned char*)base;  base += NU;
  unsigned short* Wf = (unsigned short*)base; base += (size_t)NL * 4 * 16384 * 2;
  float* ex = (float*)base;                   base += (size_t)EDGES * NH * 4;
  int* row_start = (int*)base;                base += (NNODES + 1) * 4;
  int* cnt       = (int*)base;                base += NNODES * 4;
  int* csr_src   = (int*)base;                base += EDGES * 4;
  int* csr_dst   = (int*)base;

  (void)hipMemsetAsync(cnt, 0, NNODES * sizeof(int), stream);
  k_count<<<EDGES / 256, 256, 0, stream>>>(ei, cnt);
  k_scan<<<1, 1024, 0, stream>>>(cnt, row_start);
  k_fill<<<EDGES / 256, 256, 0, stream>>>(ei, row_start, cnt, csr_src, csr_dst);
  k_wconv<<<NL * 128, 64, 0, stream>>>(Wq, Wk, Wv, Wsk, Wf);
  k_input<<<NNODES, 128, 0, stream>>>(x, Win, bin, pe, h, hb);
  for (int l = 0; l < NL; ++l) {
    k_gemm<<<dim3(NNODES / 32, 2), 256, 0, stream>>>(
        hb, Wf + (size_t)l * 4 * 16384,
        bq + l * DH, bk + l * DH, bv + l * DH, bs + l * DH, qb, kb8, vb8, xr);
    k_score<<<EDGES / 32, 256, 0, stream>>>(qb, kb8, csr_src, csr_dst, ex);
    k_attn_epi<<<NNODES / 4, 256, 0, stream>>>(vb8, ex, row_start, csr_src,
                                               h, hb, xr, Wb + l * 3 * DH, bb + l,
                                               lng + l * DH, lnb + l * DH);
  }
  k_final<<<NNODES / 4, 256, 0, stream>>>(h, Wo1, bo1, Wo2, bo2, (float*)d_out);
}

// Round 9
// 386.118 us; speedup vs baseline: 1.0824x; 1.0824x over previous
//
#include <hip/hip_runtime.h>

#define NNODES 16384
#define EDGES  262144
#define DH     128
#define NH     8
#define CH     16
#define NL     6
#define SEQ    128
#define NNPG   64

typedef short bf16x8 __attribute__((ext_vector_type(8)));
typedef float f32x4 __attribute__((ext_vector_type(4)));
typedef float f32x2 __attribute__((ext_vector_type(2)));

static __device__ __forceinline__ unsigned short f2bf(float f) {
  unsigned u = __float_as_uint(f);
  u += 0x7FFFu + ((u >> 16) & 1u);   // round-to-nearest-even
  return (unsigned short)(u >> 16);
}
static __device__ __forceinline__ float bfl(unsigned u) { return __uint_as_float(u << 16); }
static __device__ __forceinline__ float bfh(unsigned u) { return __uint_as_float(u & 0xffff0000u); }

// ---------------- h0 = x@Win + bin + pe (fp32 h + bf16 h) ----------------
__global__ __launch_bounds__(128) void k_input(const float* __restrict__ x,
    const float* __restrict__ Win, const float* __restrict__ bin,
    const float* __restrict__ pe, float* __restrict__ h,
    unsigned short* __restrict__ hb) {
  const int n = blockIdx.x, d = threadIdx.x;
  __shared__ float xs[9];
  if (d < 9) xs[d] = x[n * 9 + d];
  __syncthreads();
  float acc = bin[d];
#pragma unroll
  for (int f = 0; f < 9; ++f) acc = fmaf(xs[f], Win[f * DH + d], acc);
  const float val = acc + pe[((n / NNPG) % SEQ) * DH + d];
  h[n * DH + d] = val;
  hb[n * DH + d] = f2bf(val);
}

// ---------------- CSR build (dst-grouped), once per call ----------------
__global__ __launch_bounds__(256) void k_count(const int* __restrict__ ei,
                                               int* __restrict__ cnt) {
  const int e = blockIdx.x * 256 + threadIdx.x;
  atomicAdd(&cnt[ei[EDGES + e]], 1);
}

__global__ __launch_bounds__(1024) void k_scan(int* __restrict__ cnt,
                                               int* __restrict__ row_start) {
  __shared__ int part[1024];
  const int t = threadIdx.x;
  int loc[16];
  int s = 0;
  const int base = t * 16;
#pragma unroll
  for (int i = 0; i < 16; ++i) { loc[i] = cnt[base + i]; s += loc[i]; }
  part[t] = s;
  __syncthreads();
  for (int off = 1; off < 1024; off <<= 1) {
    int add = (t >= off) ? part[t - off] : 0;
    __syncthreads();
    part[t] += add;
    __syncthreads();
  }
  int run = (t == 0) ? 0 : part[t - 1];
#pragma unroll
  for (int i = 0; i < 16; ++i) {
    row_start[base + i] = run;
    run += loc[i];
    cnt[base + i] = 0;  // reused as cursor by k_fill
  }
  if (t == 0) row_start[NNODES] = EDGES;
}

__global__ __launch_bounds__(256) void k_fill(const int* __restrict__ ei,
    const int* __restrict__ row_start, int* __restrict__ cursor,
    int* __restrict__ csr_src) {
  const int e = blockIdx.x * 256 + threadIdx.x;
  const int d = ei[EDGES + e];
  csr_src[row_start[d] + atomicAdd(&cursor[d], 1)] = ei[e];
}

// ---------------- weight convert+swizzle to MFMA B-fragment order ----------------
__global__ __launch_bounds__(64) void k_wconv(const float* __restrict__ Wq,
    const float* __restrict__ Wk, const float* __restrict__ Wv,
    const float* __restrict__ Ws, unsigned short* __restrict__ Wf) {
  const int bid = blockIdx.x;
  const int layer = bid >> 7, rem = bid & 127;
  const int mat = rem >> 5, tile = rem & 31;
  const int nt = tile >> 2, kt = tile & 3;
  const int lane = threadIdx.x;
  const float* W = ((mat == 0) ? Wq : (mat == 1) ? Wk : (mat == 2) ? Wv : Ws)
                   + layer * DH * DH;
  const int n = nt * 16 + (lane & 15);
  const int k0 = kt * 32 + (lane >> 4) * 8;
  unsigned pk[4];
#pragma unroll
  for (int jj = 0; jj < 4; ++jj) {
    const unsigned lo = f2bf(W[(k0 + 2 * jj) * DH + n]);
    const unsigned hi = f2bf(W[(k0 + 2 * jj + 1) * DH + n]);
    pk[jj] = lo | (hi << 16);
  }
  uint4 o = {pk[0], pk[1], pk[2], pk[3]};
  *(uint4*)&Wf[(((layer * 4 + mat) * 32 + tile) * 64 + lane) * 8] = o;
}

// ---------------- fused Q/K/V/skip GEMM via bf16 MFMA ----------------
// grid (512, 2) x 256 thr; wave = one 32x64 output tile. q->bf16, k/v->fp8
// interleaved per node (K bytes 0..127, V bytes 128..255), s->fp32.
__global__ __launch_bounds__(256) void k_gemm(const unsigned short* __restrict__ hb,
    const unsigned short* __restrict__ Wf,
    const float* __restrict__ bq, const float* __restrict__ bk,
    const float* __restrict__ bv, const float* __restrict__ bs,
    unsigned short* __restrict__ qb, unsigned char* __restrict__ kv8,
    float* __restrict__ xr) {
  const int mt = blockIdx.x;
  const int wv = threadIdx.x >> 6, lane = threadIdx.x & 63;
  const int g = blockIdx.y * 4 + wv;           // col group 0..7 (64 cols)
  const int mat = g >> 1, nbase = (g & 1) * 64;
  const unsigned short* Wm = Wf + mat * 16384;
  const float* bias = (mat == 0) ? bq : (mat == 1) ? bk : (mat == 2) ? bv : bs;
  const int m0 = lane & 15, quad = lane >> 4;
  const int nt0 = (g & 1) * 4;

  const f32x4 z = {0.f, 0.f, 0.f, 0.f};
  f32x4 acc[2][4] = {{z, z, z, z}, {z, z, z, z}};
#pragma unroll
  for (int kt = 0; kt < 4; ++kt) {
    const bf16x8 a0 = *(const bf16x8*)&hb[(mt * 32 + m0) * DH + kt * 32 + quad * 8];
    const bf16x8 a1 = *(const bf16x8*)&hb[(mt * 32 + 16 + m0) * DH + kt * 32 + quad * 8];
#pragma unroll
    for (int j = 0; j < 4; ++j) {
      const bf16x8 b = *(const bf16x8*)&Wm[(((nt0 + j) * 4 + kt) * 64 + lane) * 8];
      acc[0][j] = __builtin_amdgcn_mfma_f32_16x16x32_bf16(a0, b, acc[0][j], 0, 0, 0);
      acc[1][j] = __builtin_amdgcn_mfma_f32_16x16x32_bf16(a1, b, acc[1][j], 0, 0, 0);
    }
  }
  const int kvoff = (mat == 1) ? 0 : 128;  // K first half, V second half
#pragma unroll
  for (int half = 0; half < 2; ++half) {
#pragma unroll
    for (int j = 0; j < 4; ++j) {
      const int col = nbase + j * 16 + m0;
      const float bvv = bias[col];
#pragma unroll
      for (int r = 0; r < 4; ++r) {
        const float val = acc[half][j][r] + bvv;
        const int row = mt * 32 + half * 16 + quad * 4 + r;
        if (mat == 0) {
          qb[row * DH + col] = f2bf(val);
        } else if (mat == 3) {
          xr[row * DH + col] = val;
        } else {
          // pair lanes (even,odd cols) -> 2 fp8 packed, even lane stores ushort
          const float nbv = __shfl_xor(val, 1);
          if ((lane & 1) == 0) {
            const int pk = __builtin_amdgcn_cvt_pk_fp8_f32(val, nbv, 0, false);
            *(unsigned short*)&kv8[row * 256 + kvoff + col] = (unsigned short)pk;
          }
        }
      }
    }
  }
}

// ---------------- fused attention + beta gate + residual + LayerNorm ----------------
// One wave per node, lane = es*8 + hd. Lane (es,hd) owns agg elements
// d = hd*16 + es*2 and d+1 after the cross-slot reduction.
__device__ __forceinline__ void load16bf(const unsigned short* __restrict__ p, float* r) {
  const uint4 a = *(const uint4*)p;
  const uint4 b = *(const uint4*)(p + 8);
  r[0] = bfl(a.x); r[1] = bfh(a.x); r[2] = bfl(a.y); r[3] = bfh(a.y);
  r[4] = bfl(a.z); r[5] = bfh(a.z); r[6] = bfl(a.w); r[7] = bfh(a.w);
  r[8] = bfl(b.x); r[9] = bfh(b.x); r[10] = bfl(b.y); r[11] = bfh(b.y);
  r[12] = bfl(b.z); r[13] = bfh(b.z); r[14] = bfl(b.w); r[15] = bfh(b.w);
}

__device__ __forceinline__ void decode16f8(const uint4 u, float* r) {
  f32x2 t;
  t = __builtin_amdgcn_cvt_pk_f32_fp8(u.x, false); r[0] = t[0]; r[1] = t[1];
  t = __builtin_amdgcn_cvt_pk_f32_fp8(u.x, true);  r[2] = t[0]; r[3] = t[1];
  t = __builtin_amdgcn_cvt_pk_f32_fp8(u.y, false); r[4] = t[0]; r[5] = t[1];
  t = __builtin_amdgcn_cvt_pk_f32_fp8(u.y, true);  r[6] = t[0]; r[7] = t[1];
  t = __builtin_amdgcn_cvt_pk_f32_fp8(u.z, false); r[8] = t[0]; r[9] = t[1];
  t = __builtin_amdgcn_cvt_pk_f32_fp8(u.z, true);  r[10] = t[0]; r[11] = t[1];
  t = __builtin_amdgcn_cvt_pk_f32_fp8(u.w, false); r[12] = t[0]; r[13] = t[1];
  t = __builtin_amdgcn_cvt_pk_f32_fp8(u.w, true);  r[14] = t[0]; r[15] = t[1];
}

__device__ __forceinline__ void edge_acc_m(const uint4 ku, const uint4 vu, bool valid,
    const float* __restrict__ qr, float* __restrict__ acc, float& denom) {
  float kr[16], vr[16];
  decode16f8(ku, kr);
  float dot = 0.f;
#pragma unroll
  for (int c = 0; c < 16; ++c) dot = fmaf(qr[c], kr[c], dot);
  // softmax shift-invariant; scores tiny. Masked slots contribute exactly 0.
  const float ex = valid ? __expf(dot * 0.25f) : 0.f;
  denom += ex;
  decode16f8(vu, vr);
#pragma unroll
  for (int c = 0; c < 16; ++c) acc[c] = fmaf(ex, vr[c], acc[c]);
}

__global__ __launch_bounds__(256, 4) void k_attn_epi(const unsigned short* __restrict__ qb,
    const unsigned char* __restrict__ kv8,
    const int* __restrict__ row_start, const int* __restrict__ csr_src,
    float* __restrict__ h, unsigned short* __restrict__ hb,
    const float* __restrict__ xr,
    const float* __restrict__ Wb, const float* __restrict__ bb,
    const float* __restrict__ ln_g, const float* __restrict__ ln_b) {
  const int wv = threadIdx.x >> 6, lane = threadIdx.x & 63;
  const int n = blockIdx.x * 4 + wv;
  const int es = lane >> 3, hd = lane & 7;   // 8 edge-slots x 8 heads
  const int beg = row_start[n], end = row_start[n + 1];
  // --- batched index prefetch: up to 4 edges per lane, all loads in flight ---
  const int j0 = beg + es;
  int idx[4];
#pragma unroll
  for (int t = 0; t < 4; ++t) {
    const int jt = j0 + 8 * t;
    idx[t] = (jt < end) ? csr_src[jt] : -1;
  }
  float qr[16];
  load16bf(&qb[n * DH + hd * CH], qr);
  uint4 kf[4], vf[4];
#pragma unroll
  for (int t = 0; t < 4; ++t) {
    const int s = (idx[t] >= 0) ? idx[t] : 0;
    const unsigned char* base = &kv8[s * 256 + hd * CH];
    kf[t] = *(const uint4*)base;            // K: bytes 0..127
    vf[t] = *(const uint4*)(base + 128);    // V: bytes 128..255 (same 256B record)
  }
  float acc[16] = {};
  float denom = 0.f;
#pragma unroll
  for (int t = 0; t < 4; ++t)
    edge_acc_m(kf[t], vf[t], idx[t] >= 0, qr, acc, denom);
  // rare tail (degree > 32): standard path
  for (int j = j0 + 32; j < end; j += 8) {
    const int s = csr_src[j];
    const unsigned char* base = &kv8[s * 256 + hd * CH];
    const uint4 ku = *(const uint4*)base;
    const uint4 vu = *(const uint4*)(base + 128);
    edge_acc_m(ku, vu, true, qr, acc, denom);
  }
  // reduce across the 8 edge-slots (lane bits 3..5)
#pragma unroll
  for (int off = 8; off <= 32; off <<= 1) {
    denom += __shfl_xor(denom, off);
#pragma unroll
    for (int c = 0; c < 16; ++c) acc[c] += __shfl_xor(acc[c], off);
  }
  const float inv = 1.f / (denom + 1e-16f);
  float o0 = 0.f, o1 = 0.f;
#pragma unroll
  for (int c = 0; c < 8; ++c) {  // static select (avoid dynamic reg indexing)
    if (es == c) { o0 = acc[2 * c]; o1 = acc[2 * c + 1]; }
  }
  // --- epilogue: this lane owns agg elements d0, d0+1 ---
  const int d0 = hd * CH + es * 2;
  const float ax = o0 * inv, ay = o1 * inv;
  const float2 r = *(const float2*)&xr[n * DH + d0];
  const float2 w0 = *(const float2*)&Wb[d0];
  const float2 w1 = *(const float2*)&Wb[DH + d0];
  const float2 w2 = *(const float2*)&Wb[2 * DH + d0];
  float p = ax * w0.x + ay * w0.y + r.x * w1.x + r.y * w1.y
          + (ax - r.x) * w2.x + (ay - r.y) * w2.y;
#pragma unroll
  for (int off = 1; off <= 32; off <<= 1) p += __shfl_xor(p, off);
  const float beta = 1.f / (1.f + __expf(-(p + bb[0])));
  const float2 hv = *(const float2*)&h[n * DH + d0];
  const float t0 = hv.x + beta * r.x + (1.f - beta) * ax;
  const float t1 = hv.y + beta * r.y + (1.f - beta) * ay;
  float sum = t0 + t1, sq = t0 * t0 + t1 * t1;
#pragma unroll
  for (int off = 1; off <= 32; off <<= 1) {
    sum += __shfl_xor(sum, off);
    sq  += __shfl_xor(sq, off);
  }
  const float mu = sum * (1.f / DH);
  const float rinv = rsqrtf(sq * (1.f / DH) - mu * mu + 1e-5f);
  const float2 g = *(const float2*)&ln_g[d0];
  const float2 b = *(const float2*)&ln_b[d0];
  float2 o = {(t0 - mu) * rinv * g.x + b.x, (t1 - mu) * rinv * g.y + b.y};
  *(float2*)&h[n * DH + d0] = o;
  const unsigned lo = f2bf(o.x), hi = f2bf(o.y);
  *(unsigned*)&hb[n * DH + d0] = lo | (hi << 16);
}

// ---------------- output MLP: relu(h@Wo1+bo1)@Wo2+bo2, one wave per node ----------------
__global__ __launch_bounds__(256) void k_final(const float* __restrict__ h,
    const float* __restrict__ Wo1, const float* __restrict__ bo1,
    const float* __restrict__ Wo2, const float* __restrict__ bo2,
    float* __restrict__ out) {
  __shared__ float hs[4][DH];
  const int lane = threadIdx.x & 63, wid = threadIdx.x >> 6;
  const int n = blockIdx.x * 4 + wid;
  const float2 hv = *(const float2*)&h[n * DH + lane * 2];
  hs[wid][lane * 2] = hv.x;
  hs[wid][lane * 2 + 1] = hv.y;
  __syncthreads();
  float m = bo1[lane];
#pragma unroll 16
  for (int d = 0; d < DH; ++d) m = fmaf(hs[wid][d], Wo1[d * 64 + lane], m);
  m = fmaxf(m, 0.f);
  float o0 = m * Wo2[lane * 3 + 0];
  float o1 = m * Wo2[lane * 3 + 1];
  float o2 = m * Wo2[lane * 3 + 2];
#pragma unroll
  for (int off = 32; off; off >>= 1) {
    o0 += __shfl_xor(o0, off);
    o1 += __shfl_xor(o1, off);
    o2 += __shfl_xor(o2, off);
  }
  if (lane == 0) {
    out[n * 3 + 0] = o0 + bo2[0];
    out[n * 3 + 1] = o1 + bo2[1];
    out[n * 3 + 2] = o2 + bo2[2];
  }
}

extern "C" void kernel_launch(void* const* d_in, const int* in_sizes, int n_in,
                              void* d_out, int out_size, void* d_ws, size_t ws_size,
                              hipStream_t stream) {
  const float* x   = (const float*)d_in[0];
  const int*   ei  = (const int*)d_in[1];
  const float* pe  = (const float*)d_in[2];
  const float* Win = (const float*)d_in[3];
  const float* bin = (const float*)d_in[4];
  const float* Wq  = (const float*)d_in[5];
  const float* bq  = (const float*)d_in[6];
  const float* Wk  = (const float*)d_in[7];
  const float* bk  = (const float*)d_in[8];
  const float* Wv  = (const float*)d_in[9];
  const float* bv  = (const float*)d_in[10];
  const float* Wsk = (const float*)d_in[11];
  const float* bs  = (const float*)d_in[12];
  const float* Wb  = (const float*)d_in[13];
  const float* bb  = (const float*)d_in[14];
  const float* lng = (const float*)d_in[15];
  const float* lnb = (const float*)d_in[16];
  const float* Wo1 = (const float*)d_in[17];
  const float* bo1 = (const float*)d_in[18];
  const float* Wo2 = (const float*)d_in[19];
  const float* bo2 = (const float*)d_in[20];

  const size_t NU = (size_t)NNODES * DH;
  char* base = (char*)d_ws;
  float* h   = (float*)base;                  base += NU * 4;
  float* xr  = (float*)base;                  base += NU * 4;
  unsigned short* hb = (unsigned short*)base; base += NU * 2;
  unsigned short* qb = (unsigned short*)base; base += NU * 2;
  unsigned char* kv8 = (unsigned char*)base;  base += NU * 2;  // interleaved K|V fp8
  unsigned short* Wf = (unsigned short*)base; base += (size_t)NL * 4 * 16384 * 2;
  int* row_start = (int*)base;                base += (NNODES + 1) * 4;
  int* cnt       = (int*)base;                base += NNODES * 4;
  int* csr_src   = (int*)base;

  (void)hipMemsetAsync(cnt, 0, NNODES * sizeof(int), stream);
  k_count<<<EDGES / 256, 256, 0, stream>>>(ei, cnt);
  k_scan<<<1, 1024, 0, stream>>>(cnt, row_start);
  k_fill<<<EDGES / 256, 256, 0, stream>>>(ei, row_start, cnt, csr_src);
  k_wconv<<<NL * 128, 64, 0, stream>>>(Wq, Wk, Wv, Wsk, Wf);
  k_input<<<NNODES, 128, 0, stream>>>(x, Win, bin, pe, h, hb);
  for (int l = 0; l < NL; ++l) {
    k_gemm<<<dim3(NNODES / 32, 2), 256, 0, stream>>>(
        hb, Wf + (size_t)l * 4 * 16384,
        bq + l * DH, bk + l * DH, bv + l * DH, bs + l * DH, qb, kv8, xr);
    k_attn_epi<<<NNODES / 4, 256, 0, stream>>>(qb, kv8, row_start, csr_src,
                                               h, hb, xr, Wb + l * 3 * DH, bb + l,
                                               lng + l * DH, lnb + l * DH);
  }
  k_final<<<NNODES / 4, 256, 0, stream>>>(h, Wo1, bo1, Wo2, bo2, (float*)d_out);
}